// Round 15
// baseline (687.559 us; speedup 1.0000x reference)
//
#include <hip/hip_runtime.h>

#define NN 50000
#define NE 1600000
#define DD 128
#define NLAYERS 6
#define NG 8
#define BN_EPS 1e-5f

#define NBIN 196       // bins of 256 dst nodes
#define BINCAP 10240   // avg 8163/bin, sigma~90 -> +22 sigma headroom
#define EPB 8192       // edges per k_part block
#define PB 128         // pool partial blocks
#define SREP 8         // stats replicas (atomic contention / 8)

typedef __bf16 bf16x8 __attribute__((ext_vector_type(8)));
typedef float f32x4 __attribute__((ext_vector_type(4)));

static __device__ __forceinline__ float bflo(unsigned u) {
    return __uint_as_float(u << 16);
}
static __device__ __forceinline__ float bfhi(unsigned u) {
    return __uint_as_float(u & 0xffff0000u);
}
static __device__ __forceinline__ unsigned pkbf(float a, float b) {
    __bf16 x = (__bf16)a, y = (__bf16)b;
    return (unsigned)*(unsigned short*)&x | ((unsigned)*(unsigned short*)&y << 16);
}

// ---------------- CSR build: 2-pass bin partition (R6-proven) ----------------

__global__ __launch_bounds__(1024) void k_part(const int* __restrict__ src,
                                               const int* __restrict__ dst,
                                               int* __restrict__ bincur,
                                               int2* __restrict__ scratch) {
    __shared__ int lh[NBIN], lbase[NBIN];
    const int t = threadIdx.x;
    const int e0 = blockIdx.x * EPB;
    int s8[8], d8[8];
#pragma unroll
    for (int j = 0; j < 8; ++j) {
        int e = e0 + j * 1024 + t;
        if (e < NE) { s8[j] = src[e]; d8[j] = dst[e]; }
        else d8[j] = -1;
    }
    if (t < NBIN) lh[t] = 0;
    __syncthreads();
#pragma unroll
    for (int j = 0; j < 8; ++j)
        if (d8[j] >= 0) atomicAdd(&lh[d8[j] >> 8], 1);
    __syncthreads();
    if (t < NBIN) {
        int c = lh[t];
        lbase[t] = c ? atomicAdd(&bincur[t], c) : 0;
        lh[t] = 0;
    }
    __syncthreads();
#pragma unroll
    for (int j = 0; j < 8; ++j)
        if (d8[j] >= 0) {
            int b = d8[j] >> 8;
            int p = lbase[b] + atomicAdd(&lh[b], 1);
            if (p < BINCAP) scratch[(size_t)b * BINCAP + p] = make_int2(s8[j], d8[j]);
        }
}

__global__ __launch_bounds__(256) void k_binscan(const int* __restrict__ bincur,
                                                 int* __restrict__ binbase,
                                                 int* __restrict__ off) {
    __shared__ int sc[256];
    int t = threadIdx.x;
    sc[t] = (t < NBIN) ? bincur[t] : 0;
    __syncthreads();
    for (int d = 1; d < 256; d <<= 1) {
        int v = (t >= d) ? sc[t - d] : 0;
        __syncthreads();
        sc[t] += v;
        __syncthreads();
    }
    binbase[t] = (t == 0) ? 0 : sc[t - 1];
    if (t == 0) off[NN] = NE;
}

__global__ __launch_bounds__(1024) void k_csr(const int* __restrict__ bincur,
                                              const int* __restrict__ binbase,
                                              const int2* __restrict__ scratch,
                                              int* __restrict__ off,
                                              int* __restrict__ csr,
                                              float* __restrict__ degf) {
    __shared__ int nh[256], no[256], ncur[256];
    const int t = threadIdx.x;
    const int b = blockIdx.x;
    int cnt = bincur[b]; if (cnt > BINCAP) cnt = BINCAP;
    const int base = binbase[b];
    if (t < 256) nh[t] = 0;
    __syncthreads();
    for (int i = t; i < cnt; i += 1024) {
        int2 p = scratch[(size_t)b * BINCAP + i];
        atomicAdd(&nh[p.y & 255], 1);
    }
    __syncthreads();
    if (t < 256) no[t] = nh[t];
    __syncthreads();
    for (int d = 1; d < 256; d <<= 1) {
        int v = 0;
        if (t < 256 && t >= d) v = no[t - d];
        __syncthreads();
        if (t < 256) no[t] += v;
        __syncthreads();
    }
    if (t < 256) {
        int excl = (t == 0) ? 0 : no[t - 1];
        ncur[t] = excl;
        int n = b * 256 + t;
        if (n < NN) {
            off[n] = base + excl;
            degf[n] = (float)nh[t];
        }
    }
    __syncthreads();
    for (int i = t; i < cnt; i += 1024) {
        int2 p = scratch[(size_t)b * BINCAP + i];
        int pos = atomicAdd(&ncur[p.y & 255], 1);
        csr[base + pos] = p.x;
    }
}

// ---------------- x -> bf16 copy ----------------

__global__ __launch_bounds__(256) void k_xtobf(const float* __restrict__ x,
                                               unsigned short* __restrict__ xb) {
    size_t i = (size_t)(blockIdx.x * 256 + threadIdx.x) * 8;
    float4 a = *(const float4*)(x + i);
    float4 b = *(const float4*)(x + i + 4);
    uint4 o;
    o.x = pkbf(a.x, a.y); o.y = pkbf(a.z, a.w);
    o.z = pkbf(b.x, b.y); o.w = pkbf(b.z, b.w);
    *(uint4*)(xb + i) = o;
}

// ---------------- per-layer weight prep (BN fold; stats from SREP replicas) ----

__global__ __launch_bounds__(256) void k_prep(const float* __restrict__ Wrel,
                                              const float* __restrict__ Wroot,
                                              const float* __restrict__ brel,
                                              const float* __restrict__ gammaP,
                                              const float* __restrict__ betaP,
                                              const float* __restrict__ statsP,
                                              int first,
                                              __bf16* __restrict__ wfrag,
                                              float* __restrict__ biast) {
    int b = blockIdx.x;
    if (b < 16) {
        int gid = b * 256 + threadIdx.x;       // 4096 tasks
        int pass = gid >> 11;
        int r = gid & 2047;
        int ks = r >> 9;
        int r2 = r & 511;
        int ct = r2 >> 6;
        int lane = r2 & 63;
        int col = ct * 16 + (lane & 15);
        int kb = ks * 32 + (lane >> 4) * 8;
        const float* W = pass ? Wroot : Wrel;
        bf16x8 vh, vl;
#pragma unroll
        for (int j = 0; j < 8; ++j) {
            int k = kb + j;
            float s = 1.f;
            if (!first) {
                float sm = 0.f, qm = 0.f;
#pragma unroll
                for (int rr = 0; rr < SREP; ++rr) {
                    sm += statsP[rr * 256 + k];
                    qm += statsP[rr * 256 + DD + k];
                }
                float m = sm * (1.0f / NN);
                float var = qm * (1.0f / NN) - m * m;
                s = gammaP[k] * rsqrtf(var + BN_EPS);
            }
            float v = s * W[(size_t)k * DD + col];
            __bf16 hb = (__bf16)v;
            vh[j] = hb;
            vl[j] = (__bf16)(v - (float)hb);
        }
        size_t oh = (((size_t)(pass * 2 + 0) * 4 + ks) * 8 + ct) * 512 + lane * 8;
        *(bf16x8*)(wfrag + oh) = vh;
        *(bf16x8*)(wfrag + oh + 16384) = vl;
    } else {
        int t = threadIdx.x;
        int col = t & 127;
        bool isT = t >= 128;
        const float* W = isT ? Wrel : Wroot;
        float acc = 0.f;
        if (!first) {
            for (int k = 0; k < DD; ++k) {
                float sm = 0.f, qm = 0.f;
#pragma unroll
                for (int rr = 0; rr < SREP; ++rr) {
                    sm += statsP[rr * 256 + k];
                    qm += statsP[rr * 256 + DD + k];
                }
                float m = sm * (1.0f / NN);
                float var = qm * (1.0f / NN) - m * m;
                float s = gammaP[k] * rsqrtf(var + BN_EPS);
                float tv = betaP[k] - m * s;
                acc = fmaf(tv, W[(size_t)k * DD + col], acc);
            }
        }
        if (isT) biast[128 + col] = acc;
        else biast[col] = brel[col] + acc;
    }
}

// ---------------- fused layer: 16 nodes/block, interleaved 4-stream gather ------
// Wave w gathers its 4 nodes SIMULTANEOUSLY (4 independent acc chains, 8 uint4
// loads in flight) then 16x128 MFMA gemm from 8KB swizzled LDS A-tile.

static __device__ __forceinline__ void acc8(float (&A)[8], uint4 v) {
    A[0] += bflo(v.x); A[1] += bfhi(v.x);
    A[2] += bflo(v.y); A[3] += bfhi(v.y);
    A[4] += bflo(v.z); A[5] += bfhi(v.z);
    A[6] += bflo(v.w); A[7] += bfhi(v.w);
}

static __device__ __forceinline__ void finish_node(float (&A)[8], int e, int hi,
                                                   int q, int colo,
                                                   const uint4* __restrict__ hp,
                                                   const int* __restrict__ csr,
                                                   int r, __bf16* A_hi, __bf16* A_lo,
                                                   int lane) {
    for (; e + 4 <= hi; e += 4) {
        int s = csr[e + q];
        acc8(A, hp[(size_t)s * 16 + colo]);
    }
#pragma unroll
    for (int j = 0; j < 8; ++j) {
        A[j] += __shfl_xor(A[j], 16);
        A[j] += __shfl_xor(A[j], 32);
    }
    for (; e < hi; ++e) {  // singles: all lanes add identical values (replicas stay equal)
        int s = csr[e];
        acc8(A, hp[(size_t)s * 16 + colo]);
    }
    if (lane < 16) {
        bf16x8 vh, vl;
#pragma unroll
        for (int j = 0; j < 8; ++j) {
            __bf16 hv = (__bf16)A[j];
            vh[j] = hv;
            vl[j] = (__bf16)(A[j] - (float)hv);
        }
        int eo = r * 128 + ((colo ^ (r & 7)) << 3);
        *(bf16x8*)(A_hi + eo) = vh;
        *(bf16x8*)(A_lo + eo) = vl;
    }
}

__global__ __launch_bounds__(256, 5) void k_layer(const unsigned short* __restrict__ hb_in,
                                                  const int* __restrict__ off,
                                                  const int* __restrict__ csr,
                                                  const __bf16* __restrict__ wfrag,
                                                  const float* __restrict__ biast,
                                                  const float* __restrict__ degf,
                                                  unsigned short* __restrict__ hb_out,
                                                  float* __restrict__ stats) {
    __shared__ __align__(16) __bf16 A_hi[16 * 128];
    __shared__ __align__(16) __bf16 A_lo[16 * 128];
    __shared__ float sb[4][32], qb[4][32];
    const int tid = threadIdx.x;
    const int w = tid >> 6, lane = tid & 63;
    const int r0 = blockIdx.x * 16;          // 3125 blocks cover NN exactly

    // ---- Phase G: interleaved gather of rows w*4 .. w*4+3 ----
    {
        const int q = lane >> 4;
        const int colo = lane & 15;
        const uint4* hp = (const uint4*)hb_in;
        const int nb = r0 + w * 4;
        int e0 = off[nb],     h0 = off[nb + 1];
        int e1 = h0,          h1 = off[nb + 2];
        int e2 = h1,          h2 = off[nb + 3];
        int e3 = h2,          h3 = off[nb + 4];
        float A0[8] = {}, A1[8] = {}, A2[8] = {}, A3[8] = {};
        // common loop: 8 edges per node per iter -> 8 independent uint4 loads in flight
        while (e0 + 8 <= h0 && e1 + 8 <= h1 && e2 + 8 <= h2 && e3 + 8 <= h3) {
            int sa0 = csr[e0 + q],     sa1 = csr[e1 + q],     sa2 = csr[e2 + q],     sa3 = csr[e3 + q];
            int sb0 = csr[e0 + 4 + q], sb1 = csr[e1 + 4 + q], sb2 = csr[e2 + 4 + q], sb3 = csr[e3 + 4 + q];
            uint4 va0 = hp[(size_t)sa0 * 16 + colo];
            uint4 va1 = hp[(size_t)sa1 * 16 + colo];
            uint4 va2 = hp[(size_t)sa2 * 16 + colo];
            uint4 va3 = hp[(size_t)sa3 * 16 + colo];
            uint4 vb0 = hp[(size_t)sb0 * 16 + colo];
            uint4 vb1 = hp[(size_t)sb1 * 16 + colo];
            uint4 vb2 = hp[(size_t)sb2 * 16 + colo];
            uint4 vb3 = hp[(size_t)sb3 * 16 + colo];
            acc8(A0, va0); acc8(A1, va1); acc8(A2, va2); acc8(A3, va3);
            acc8(A0, vb0); acc8(A1, vb1); acc8(A2, vb2); acc8(A3, vb3);
            e0 += 8; e1 += 8; e2 += 8; e3 += 8;
        }
        // per-node tails (4-wide loop, reduce, singles) + LDS write
        finish_node(A0, e0, h0, q, colo, hp, csr, w * 4 + 0, A_hi, A_lo, lane);
        finish_node(A1, e1, h1, q, colo, hp, csr, w * 4 + 1, A_hi, A_lo, lane);
        finish_node(A2, e2, h2, q, colo, hp, csr, w * 4 + 2, A_hi, A_lo, lane);
        finish_node(A3, e3, h3, q, colo, hp, csr, w * 4 + 3, A_hi, A_lo, lane);
    }
    __syncthreads();

    // ---- Phase M: 16x128 gemm; wave w = col-group (32 cols) ----
    const int cg = w;
    const int lrow = lane & 15, lk = lane >> 4;
    const int nA = r0 + lrow;                // < NN always

    f32x4 acc[2];
    acc[0] = (f32x4){0.f, 0.f, 0.f, 0.f};
    acc[1] = (f32x4){0.f, 0.f, 0.f, 0.f};

#pragma unroll
    for (int pass = 0; pass < 2; ++pass) {
#pragma unroll
        for (int ks = 0; ks < 4; ++ks) {
            bf16x8 ah, al;
            if (pass == 0) {
                int chA = ks * 4 + lk;
                int eoA = lrow * 128 + ((chA ^ (lrow & 7)) << 3);
                ah = *(const bf16x8*)(A_hi + eoA);
                al = *(const bf16x8*)(A_lo + eoA);
            } else {
                ah = *(const bf16x8*)(hb_in + (size_t)nA * DD + ks * 32 + lk * 8);
            }
            const __bf16* bh_base = wfrag + ((size_t)(pass * 2 + 0) * 4 + ks) * 4096
                                    + (cg * 2) * 512 + lane * 8;
            const __bf16* bl_base = wfrag + ((size_t)(pass * 2 + 1) * 4 + ks) * 4096
                                    + (cg * 2) * 512 + lane * 8;
#pragma unroll
            for (int ctl = 0; ctl < 2; ++ctl) {
                bf16x8 bh = *(const bf16x8*)(bh_base + ctl * 512);
                bf16x8 bl = *(const bf16x8*)(bl_base + ctl * 512);
                acc[ctl] = __builtin_amdgcn_mfma_f32_16x16x32_bf16(ah, bh, acc[ctl], 0, 0, 0);
                if (pass == 0)
                    acc[ctl] = __builtin_amdgcn_mfma_f32_16x16x32_bf16(al, bh, acc[ctl], 0, 0, 0);
                acc[ctl] = __builtin_amdgcn_mfma_f32_16x16x32_bf16(ah, bl, acc[ctl], 0, 0, 0);
            }
        }
    }

    // ---- epilogue: bias + relu + store + column stats (SREP-replicated) ----
    float cs[2], cq[2];
    cs[0] = cs[1] = cq[0] = cq[1] = 0.f;
#pragma unroll
    for (int ctl = 0; ctl < 2; ++ctl) {
        int col = (cg * 2 + ctl) * 16 + lrow;
        float bt = biast[col];
        float tr = biast[128 + col];
#pragma unroll
        for (int q2 = 0; q2 < 4; ++q2) {
            int n = r0 + lk * 4 + q2;
            float o = fmaxf(acc[ctl][q2] + bt + degf[n] * tr, 0.f);
            __bf16 ob = (__bf16)o;
            hb_out[(size_t)n * DD + col] = *(unsigned short*)&ob;
            cs[ctl] += o;
            cq[ctl] += o * o;
        }
    }
#pragma unroll
    for (int ctl = 0; ctl < 2; ++ctl) {
        cs[ctl] += __shfl_xor(cs[ctl], 16);
        cs[ctl] += __shfl_xor(cs[ctl], 32);
        cq[ctl] += __shfl_xor(cq[ctl], 16);
        cq[ctl] += __shfl_xor(cq[ctl], 32);
    }
    if (lane < 16) {
#pragma unroll
        for (int ctl = 0; ctl < 2; ++ctl) {
            sb[cg][ctl * 16 + lrow] = cs[ctl];
            qb[cg][ctl * 16 + lrow] = cq[ctl];
        }
    }
    __syncthreads();
    float* srep = stats + (size_t)(blockIdx.x & (SREP - 1)) * 256;
    if (tid < 128) {
        atomicAdd(&srep[tid], sb[tid >> 5][tid & 31]);
    } else if (tid < 256) {
        int c2 = tid - 128;
        atomicAdd(&srep[DD + c2], qb[c2 >> 5][c2 & 31]);
    }
}

// ---------------- pooling stage 1: per-block partials, no global atomics --------

__global__ __launch_bounds__(256) void k_pool(const unsigned short* __restrict__ hb,
                                              const int* __restrict__ batch,
                                              float* __restrict__ pp,   // [PB][NG][DD]
                                              int* __restrict__ pc) {   // [PB][NG]
    __shared__ float sacc[NG][DD];
    __shared__ int scnt[NG];
    const int tid = threadIdx.x;
    const int rs = tid >> 4;
    const int co = tid & 15;
#pragma unroll
    for (int j = 0; j < 4; ++j) sacc[(tid * 4 + j) >> 7][(tid * 4 + j) & 127] = 0.f;
    if (tid < NG) scnt[tid] = 0;
    __syncthreads();
    const int chunk = (NN + PB - 1) / PB;
    int lo = blockIdx.x * chunk;
    int hi = lo + chunk; if (hi > NN) hi = NN;
    const uint4* hp = (const uint4*)hb;
    float a[8] = {};
    int cur = -1, cnt = 0;
    for (int n = lo + rs; n < hi; n += 16) {
        int g = batch[n];
        if (g != cur) {
            if (cur >= 0) {
#pragma unroll
                for (int j = 0; j < 8; ++j) atomicAdd(&sacc[cur][co * 8 + j], a[j]);
                if (co == 0) atomicAdd(&scnt[cur], cnt);
#pragma unroll
                for (int j = 0; j < 8; ++j) a[j] = 0.f;
                cnt = 0;
            }
            cur = g;
        }
        uint4 v = hp[(size_t)n * 16 + co];
        a[0] += bflo(v.x); a[1] += bfhi(v.x);
        a[2] += bflo(v.y); a[3] += bfhi(v.y);
        a[4] += bflo(v.z); a[5] += bfhi(v.z);
        a[6] += bflo(v.w); a[7] += bfhi(v.w);
        cnt++;
    }
    if (cur >= 0) {
#pragma unroll
        for (int j = 0; j < 8; ++j) atomicAdd(&sacc[cur][co * 8 + j], a[j]);
        if (co == 0) atomicAdd(&scnt[cur], cnt);
    }
    __syncthreads();
    float* ppb = pp + (size_t)blockIdx.x * NG * DD;
#pragma unroll
    for (int j = 0; j < 4; ++j) {
        int idx = tid * 4 + j;
        ppb[idx] = sacc[idx >> 7][idx & 127];
    }
    if (tid < NG) pc[blockIdx.x * NG + tid] = scnt[tid];
}

// ---------------- head: reduce partials + final BN + dense + mu ----------------

__global__ __launch_bounds__(1024) void k_head(const float* __restrict__ pp,
                                               const int* __restrict__ pc,
                                               const float* __restrict__ statsP,
                                               const float* __restrict__ gammaP,
                                               const float* __restrict__ betaP,
                                               const float* __restrict__ dw,
                                               const float* __restrict__ db,
                                               const float* __restrict__ muw,
                                               const float* __restrict__ mub,
                                               float* __restrict__ out) {
    __shared__ float pm[NG][DD];
    __shared__ float zs[NG][DD];
    int t = threadIdx.x;
    int g = t >> 7, c = t & 127;
    float sum = 0.f;
    for (int b = 0; b < PB; ++b)
        sum += pp[(size_t)b * NG * DD + g * DD + c];
    int cnti = 0;
    for (int b = 0; b < PB; ++b)
        cnti += pc[b * NG + g];
    float cntg = (float)cnti;
    float sm = 0.f, qm = 0.f;
#pragma unroll
    for (int rr = 0; rr < SREP; ++rr) {
        sm += statsP[rr * 256 + c];
        qm += statsP[rr * 256 + DD + c];
    }
    float m = sm * (1.0f / NN);
    float var = qm * (1.0f / NN) - m * m;
    float s = gammaP[c] * rsqrtf(var + BN_EPS);
    float tv = betaP[c] - m * s;
    pm[g][c] = fmaf(s, sum, tv * cntg) / fmaxf(cntg, 1.0f);
    __syncthreads();
    float acc = 0.f;
    for (int k = 0; k < DD; ++k)
        acc = fmaf(pm[g][k], dw[k * DD + c], acc);
    float z = fmaxf(acc + db[c], 0.f);
    zs[g][c] = z * muw[c];
    __syncthreads();
    if (c == 0) {
        float s2 = 0.f;
        for (int k = 0; k < DD; ++k) s2 += zs[g][k];
        out[g] = s2 + mub[0];
    }
}

// ---------------- host ----------------

extern "C" void kernel_launch(void* const* d_in, const int* in_sizes, int n_in,
                              void* d_out, int out_size, void* d_ws, size_t ws_size,
                              hipStream_t stream) {
    const float* x      = (const float*)d_in[0];
    const int*   ei     = (const int*)d_in[1];
    const int*   batch  = (const int*)d_in[2];
    const float* W_rel  = (const float*)d_in[3];
    const float* b_rel  = (const float*)d_in[4];
    const float* W_root = (const float*)d_in[5];
    const float* gamma  = (const float*)d_in[6];
    const float* beta   = (const float*)d_in[7];
    const float* dw     = (const float*)d_in[8];
    const float* db     = (const float*)d_in[9];
    const float* muw    = (const float*)d_in[10];
    const float* mub    = (const float*)d_in[11];
    float* out = (float*)d_out;

    char* w = (char*)d_ws;
    auto alloc = [&](size_t bytes) {
        char* p = w;
        w += (bytes + 255) & ~(size_t)255;
        return p;
    };
    int*    off      = (int*)alloc((size_t)(NN + 1) * 4);
    int*    csr      = (int*)alloc((size_t)NE * 4);
    char*   bigbuf   = (char*)alloc((size_t)NN * DD * 4);   // CSR partition scratch
    unsigned short* hbA = (unsigned short*)alloc((size_t)NN * DD * 2);
    unsigned short* hbB = (unsigned short*)alloc((size_t)NN * DD * 2);
    float*  degf     = (float*)alloc((size_t)NN * 4);
    float*  statsBuf = (float*)alloc((size_t)NLAYERS * SREP * 2 * DD * 4);
    float*  biast    = (float*)alloc(2 * DD * 4);
    float*  pp       = (float*)alloc((size_t)PB * NG * DD * 4);
    int*    pc       = (int*)alloc((size_t)PB * NG * 4);
    int*    bincur   = (int*)alloc(256 * 4);
    int*    binbase  = (int*)alloc(256 * 4);
    __bf16* wfrag    = (__bf16*)alloc((size_t)65536 * 2);   // 128 KB, rewritten per layer

    const int* src = ei;
    const int* dst = ei + NE;
    int2* scratch = (int2*)bigbuf;  // 16.06 MB (CSR build only)

    hipMemsetAsync(bincur, 0, 256 * 4, stream);
    hipMemsetAsync(statsBuf, 0, (size_t)NLAYERS * SREP * 2 * DD * 4, stream);
    k_part<<<(NE + EPB - 1) / EPB, 1024, 0, stream>>>(src, dst, bincur, scratch);
    k_binscan<<<1, 256, 0, stream>>>(bincur, binbase, off);
    k_csr<<<NBIN, 1024, 0, stream>>>(bincur, binbase, scratch, off, csr, degf);
    k_xtobf<<<(NN * DD / 8 + 255) / 256, 256, 0, stream>>>(x, hbA);

    const unsigned short* hcur = hbA;
    unsigned short* bufs[2] = {hbB, hbA};
    for (int i = 0; i < NLAYERS; ++i) {
        unsigned short* hnext = bufs[i & 1];
        k_prep<<<17, 256, 0, stream>>>(W_rel + (size_t)i * DD * DD,
                                       W_root + (size_t)i * DD * DD,
                                       b_rel + (size_t)i * DD,
                                       gamma + (size_t)(i - 1) * DD,
                                       beta + (size_t)(i - 1) * DD,
                                       statsBuf + (size_t)(i - 1) * SREP * 2 * DD,
                                       i == 0 ? 1 : 0, wfrag, biast);
        k_layer<<<NN / 16, 256, 0, stream>>>(hcur, off, csr, wfrag, biast, degf,
                                             hnext, statsBuf + (size_t)i * SREP * 2 * DD);
        hcur = hnext;
    }
    k_pool<<<PB, 256, 0, stream>>>(hcur, batch, pp, pc);
    k_head<<<1, 1024, 0, stream>>>(pp, pc,
                                   statsBuf + (size_t)(NLAYERS - 1) * SREP * 2 * DD,
                                   gamma + (size_t)(NLAYERS - 1) * DD,
                                   beta + (size_t)(NLAYERS - 1) * DD,
                                   dw, db, muw, mub, out);
}

// Round 16
// 513.807 us; speedup vs baseline: 1.3382x; 1.3382x over previous
//
#include <hip/hip_runtime.h>

#define NN 50000
#define NE 1600000
#define DD 128
#define NLAYERS 6
#define NG 8
#define BN_EPS 1e-5f

#define NBIN 196       // bins of 256 dst nodes
#define BINCAP 10240   // avg 8163/bin, sigma~90 -> +22 sigma headroom
#define EPB 8192       // edges per k_part block
#define PB 128         // pool partial blocks
#define SREP 8         // stats replicas (atomic contention / 8)

typedef __bf16 bf16x8 __attribute__((ext_vector_type(8)));
typedef float f32x4 __attribute__((ext_vector_type(4)));

static __device__ __forceinline__ float bflo(unsigned u) {
    return __uint_as_float(u << 16);
}
static __device__ __forceinline__ float bfhi(unsigned u) {
    return __uint_as_float(u & 0xffff0000u);
}
static __device__ __forceinline__ unsigned pkbf(float a, float b) {
    __bf16 x = (__bf16)a, y = (__bf16)b;
    return (unsigned)*(unsigned short*)&x | ((unsigned)*(unsigned short*)&y << 16);
}

// ---------------- CSR build: 2-pass bin partition, packed 4B scratch ----------
// scratch entry = (src << 8) | (dst & 255)   [src < 65536, bin-local dst]

__global__ __launch_bounds__(1024) void k_part(const int* __restrict__ src,
                                               const int* __restrict__ dst,
                                               int* __restrict__ bincur,
                                               unsigned* __restrict__ scratch) {
    __shared__ int lh[NBIN], lbase[NBIN];
    const int t = threadIdx.x;
    const int e0 = blockIdx.x * EPB;
    int s8[8], d8[8];
#pragma unroll
    for (int j = 0; j < 8; ++j) {
        int e = e0 + j * 1024 + t;
        if (e < NE) { s8[j] = src[e]; d8[j] = dst[e]; }
        else d8[j] = -1;
    }
    if (t < NBIN) lh[t] = 0;
    __syncthreads();
#pragma unroll
    for (int j = 0; j < 8; ++j)
        if (d8[j] >= 0) atomicAdd(&lh[d8[j] >> 8], 1);
    __syncthreads();
    if (t < NBIN) {
        int c = lh[t];
        lbase[t] = c ? atomicAdd(&bincur[t], c) : 0;
        lh[t] = 0;
    }
    __syncthreads();
#pragma unroll
    for (int j = 0; j < 8; ++j)
        if (d8[j] >= 0) {
            int b = d8[j] >> 8;
            int p = lbase[b] + atomicAdd(&lh[b], 1);
            if (p < BINCAP)
                scratch[(size_t)b * BINCAP + p] = ((unsigned)s8[j] << 8) | (unsigned)(d8[j] & 255);
        }
}

__global__ __launch_bounds__(256) void k_binscan(const int* __restrict__ bincur,
                                                 int* __restrict__ binbase,
                                                 int* __restrict__ off) {
    __shared__ int sc[256];
    int t = threadIdx.x;
    sc[t] = (t < NBIN) ? bincur[t] : 0;
    __syncthreads();
    for (int d = 1; d < 256; d <<= 1) {
        int v = (t >= d) ? sc[t - d] : 0;
        __syncthreads();
        sc[t] += v;
        __syncthreads();
    }
    binbase[t] = (t == 0) ? 0 : sc[t - 1];
    if (t == 0) off[NN] = NE;
}

__global__ __launch_bounds__(1024) void k_csr(const int* __restrict__ bincur,
                                              const int* __restrict__ binbase,
                                              const unsigned* __restrict__ scratch,
                                              int* __restrict__ off,
                                              int* __restrict__ csr,
                                              float* __restrict__ degf) {
    __shared__ int nh[256], no[256], ncur[256];
    const int t = threadIdx.x;
    const int b = blockIdx.x;
    int cnt = bincur[b]; if (cnt > BINCAP) cnt = BINCAP;
    const int base = binbase[b];
    if (t < 256) nh[t] = 0;
    __syncthreads();
    for (int i = t; i < cnt; i += 1024) {
        unsigned p = scratch[(size_t)b * BINCAP + i];
        atomicAdd(&nh[p & 255], 1);
    }
    __syncthreads();
    if (t < 256) no[t] = nh[t];
    __syncthreads();
    for (int d = 1; d < 256; d <<= 1) {
        int v = 0;
        if (t < 256 && t >= d) v = no[t - d];
        __syncthreads();
        if (t < 256) no[t] += v;
        __syncthreads();
    }
    if (t < 256) {
        int excl = (t == 0) ? 0 : no[t - 1];
        ncur[t] = excl;
        int n = b * 256 + t;
        if (n < NN) {
            off[n] = base + excl;
            degf[n] = (float)nh[t];
        }
    }
    __syncthreads();
    for (int i = t; i < cnt; i += 1024) {
        unsigned p = scratch[(size_t)b * BINCAP + i];
        int pos = atomicAdd(&ncur[p & 255], 1);
        csr[base + pos] = (int)(p >> 8);
    }
}

// ---------------- x -> bf16 copy ----------------

__global__ __launch_bounds__(256) void k_xtobf(const float* __restrict__ x,
                                               unsigned short* __restrict__ xb) {
    size_t i = (size_t)(blockIdx.x * 256 + threadIdx.x) * 8;
    float4 a = *(const float4*)(x + i);
    float4 b = *(const float4*)(x + i + 4);
    uint4 o;
    o.x = pkbf(a.x, a.y); o.y = pkbf(a.z, a.w);
    o.z = pkbf(b.x, b.y); o.w = pkbf(b.z, b.w);
    *(uint4*)(xb + i) = o;
}

// ---------------- per-layer weight prep (BN fold; LDS-cached s/tv) ------------

__global__ __launch_bounds__(256) void k_prep(const float* __restrict__ Wrel,
                                              const float* __restrict__ Wroot,
                                              const float* __restrict__ brel,
                                              const float* __restrict__ gammaP,
                                              const float* __restrict__ betaP,
                                              const float* __restrict__ statsP,
                                              int first,
                                              __bf16* __restrict__ wfrag,
                                              float* __restrict__ biast) {
    __shared__ float ls[DD], lt[DD];
    int t0 = threadIdx.x;
    if (t0 < DD) {
        float s = 1.f, tv = 0.f;
        if (!first) {
            float sm = 0.f, qm = 0.f;
#pragma unroll
            for (int rr = 0; rr < SREP; ++rr) {
                sm += statsP[rr * 256 + t0];
                qm += statsP[rr * 256 + DD + t0];
            }
            float m = sm * (1.0f / NN);
            float var = qm * (1.0f / NN) - m * m;
            s = gammaP[t0] * rsqrtf(var + BN_EPS);
            tv = betaP[t0] - m * s;
        }
        ls[t0] = s;
        lt[t0] = tv;
    }
    __syncthreads();
    int b = blockIdx.x;
    if (b < 16) {
        int gid = b * 256 + threadIdx.x;       // 4096 tasks
        int pass = gid >> 11;
        int r = gid & 2047;
        int ks = r >> 9;
        int r2 = r & 511;
        int ct = r2 >> 6;
        int lane = r2 & 63;
        int col = ct * 16 + (lane & 15);
        int kb = ks * 32 + (lane >> 4) * 8;
        const float* W = pass ? Wroot : Wrel;
        bf16x8 vh, vl;
#pragma unroll
        for (int j = 0; j < 8; ++j) {
            int k = kb + j;
            float v = ls[k] * W[(size_t)k * DD + col];
            __bf16 hb = (__bf16)v;
            vh[j] = hb;
            vl[j] = (__bf16)(v - (float)hb);
        }
        size_t oh = (((size_t)(pass * 2 + 0) * 4 + ks) * 8 + ct) * 512 + lane * 8;
        *(bf16x8*)(wfrag + oh) = vh;
        *(bf16x8*)(wfrag + oh + 16384) = vl;
    } else {
        int t = threadIdx.x;
        int col = t & 127;
        bool isT = t >= 128;
        const float* W = isT ? Wrel : Wroot;
        float acc = 0.f;
        if (!first) {
            for (int k = 0; k < DD; ++k)
                acc = fmaf(lt[k], W[(size_t)k * DD + col], acc);
        }
        if (isT) biast[128 + col] = acc;
        else biast[col] = brel[col] + acc;
    }
}

// ---------------- fused layer (R14-proven): 16 nodes/block, serial 4/wave ------

#define ACC8(v) {                                              \
    a0 += bflo(v.x); a1 += bfhi(v.x);                          \
    a2 += bflo(v.y); a3 += bfhi(v.y);                          \
    a4 += bflo(v.z); a5 += bfhi(v.z);                          \
    a6 += bflo(v.w); a7 += bfhi(v.w); }

__global__ __launch_bounds__(256, 6) void k_layer(const unsigned short* __restrict__ hb_in,
                                                  const int* __restrict__ off,
                                                  const int* __restrict__ csr,
                                                  const __bf16* __restrict__ wfrag,
                                                  const float* __restrict__ biast,
                                                  const float* __restrict__ degf,
                                                  unsigned short* __restrict__ hb_out,
                                                  float* __restrict__ stats) {
    __shared__ __align__(16) __bf16 A_hi[16 * 128];
    __shared__ __align__(16) __bf16 A_lo[16 * 128];
    __shared__ float sb[4][32], qb[4][32];
    const int tid = threadIdx.x;
    const int w = tid >> 6, lane = tid & 63;
    const int r0 = blockIdx.x * 16;          // 3125 blocks cover NN exactly

    // ---- Phase G: wave w gathers rows w*4 .. w*4+3 ----
    {
        const int q = lane >> 4;
        const int colo = lane & 15;
        const uint4* hp = (const uint4*)hb_in;
#pragma unroll 1
        for (int rr = 0; rr < 4; ++rr) {
            int r = w * 4 + rr;
            int n = r0 + r;
            float a0 = 0.f, a1 = 0.f, a2 = 0.f, a3 = 0.f,
                  a4 = 0.f, a5 = 0.f, a6 = 0.f, a7 = 0.f;
            int lo = off[n], hi = off[n + 1];
            int e = lo;
            for (; e + 16 <= hi; e += 16) {
                int s0 = csr[e + q];
                int s1 = csr[e + 4 + q];
                int s2 = csr[e + 8 + q];
                int s3 = csr[e + 12 + q];
                uint4 v0 = hp[(size_t)s0 * 16 + colo];
                uint4 v1 = hp[(size_t)s1 * 16 + colo];
                uint4 v2 = hp[(size_t)s2 * 16 + colo];
                uint4 v3 = hp[(size_t)s3 * 16 + colo];
                ACC8(v0); ACC8(v1); ACC8(v2); ACC8(v3);
            }
            for (; e + 4 <= hi; e += 4) {
                int s = csr[e + q];
                uint4 v = hp[(size_t)s * 16 + colo];
                ACC8(v);
            }
            a0 += __shfl_xor(a0, 16); a1 += __shfl_xor(a1, 16);
            a2 += __shfl_xor(a2, 16); a3 += __shfl_xor(a3, 16);
            a4 += __shfl_xor(a4, 16); a5 += __shfl_xor(a5, 16);
            a6 += __shfl_xor(a6, 16); a7 += __shfl_xor(a7, 16);
            a0 += __shfl_xor(a0, 32); a1 += __shfl_xor(a1, 32);
            a2 += __shfl_xor(a2, 32); a3 += __shfl_xor(a3, 32);
            a4 += __shfl_xor(a4, 32); a5 += __shfl_xor(a5, 32);
            a6 += __shfl_xor(a6, 32); a7 += __shfl_xor(a7, 32);
            for (; e < hi; ++e) {  // tail: all lanes add identical values
                int s = csr[e];
                uint4 v = hp[(size_t)s * 16 + colo];
                ACC8(v);
            }
            if (lane < 16) {
                float av[8] = {a0, a1, a2, a3, a4, a5, a6, a7};
                bf16x8 vh, vl;
#pragma unroll
                for (int j = 0; j < 8; ++j) {
                    __bf16 hv = (__bf16)av[j];
                    vh[j] = hv;
                    vl[j] = (__bf16)(av[j] - (float)hv);
                }
                int eo = r * 128 + ((colo ^ (r & 7)) << 3);
                *(bf16x8*)(A_hi + eo) = vh;
                *(bf16x8*)(A_lo + eo) = vl;
            }
        }
    }
    __syncthreads();

    // ---- Phase M: 16x128 gemm; wave w = col-group (32 cols) ----
    const int cg = w;
    const int lrow = lane & 15, lk = lane >> 4;
    const int nA = r0 + lrow;                // < NN always

    f32x4 acc[2];
    acc[0] = (f32x4){0.f, 0.f, 0.f, 0.f};
    acc[1] = (f32x4){0.f, 0.f, 0.f, 0.f};

#pragma unroll
    for (int pass = 0; pass < 2; ++pass) {
#pragma unroll
        for (int ks = 0; ks < 4; ++ks) {
            bf16x8 ah, al;
            if (pass == 0) {
                int chA = ks * 4 + lk;
                int eoA = lrow * 128 + ((chA ^ (lrow & 7)) << 3);
                ah = *(const bf16x8*)(A_hi + eoA);
                al = *(const bf16x8*)(A_lo + eoA);
            } else {
                ah = *(const bf16x8*)(hb_in + (size_t)nA * DD + ks * 32 + lk * 8);
            }
            const __bf16* bh_base = wfrag + ((size_t)(pass * 2 + 0) * 4 + ks) * 4096
                                    + (cg * 2) * 512 + lane * 8;
            const __bf16* bl_base = wfrag + ((size_t)(pass * 2 + 1) * 4 + ks) * 4096
                                    + (cg * 2) * 512 + lane * 8;
#pragma unroll
            for (int ctl = 0; ctl < 2; ++ctl) {
                bf16x8 bh = *(const bf16x8*)(bh_base + ctl * 512);
                bf16x8 bl = *(const bf16x8*)(bl_base + ctl * 512);
                acc[ctl] = __builtin_amdgcn_mfma_f32_16x16x32_bf16(ah, bh, acc[ctl], 0, 0, 0);
                if (pass == 0)
                    acc[ctl] = __builtin_amdgcn_mfma_f32_16x16x32_bf16(al, bh, acc[ctl], 0, 0, 0);
                acc[ctl] = __builtin_amdgcn_mfma_f32_16x16x32_bf16(ah, bl, acc[ctl], 0, 0, 0);
            }
        }
    }

    // ---- epilogue: bias + relu + store + column stats (SREP-replicated) ----
    float cs[2], cq[2];
    cs[0] = cs[1] = cq[0] = cq[1] = 0.f;
#pragma unroll
    for (int ctl = 0; ctl < 2; ++ctl) {
        int col = (cg * 2 + ctl) * 16 + lrow;
        float bt = biast[col];
        float tr = biast[128 + col];
#pragma unroll
        for (int q2 = 0; q2 < 4; ++q2) {
            int n = r0 + lk * 4 + q2;
            float o = fmaxf(acc[ctl][q2] + bt + degf[n] * tr, 0.f);
            __bf16 ob = (__bf16)o;
            hb_out[(size_t)n * DD + col] = *(unsigned short*)&ob;
            cs[ctl] += o;
            cq[ctl] += o * o;
        }
    }
#pragma unroll
    for (int ctl = 0; ctl < 2; ++ctl) {
        cs[ctl] += __shfl_xor(cs[ctl], 16);
        cs[ctl] += __shfl_xor(cs[ctl], 32);
        cq[ctl] += __shfl_xor(cq[ctl], 16);
        cq[ctl] += __shfl_xor(cq[ctl], 32);
    }
    if (lane < 16) {
#pragma unroll
        for (int ctl = 0; ctl < 2; ++ctl) {
            sb[cg][ctl * 16 + lrow] = cs[ctl];
            qb[cg][ctl * 16 + lrow] = cq[ctl];
        }
    }
    __syncthreads();
    float* srep = stats + (size_t)(blockIdx.x & (SREP - 1)) * 256;
    if (tid < 128) {
        atomicAdd(&srep[tid], sb[tid >> 5][tid & 31]);
    } else if (tid < 256) {
        int c2 = tid - 128;
        atomicAdd(&srep[DD + c2], qb[c2 >> 5][c2 & 31]);
    }
}

// ---------------- pooling stage 1: per-block partials, no global atomics --------

__global__ __launch_bounds__(256) void k_pool(const unsigned short* __restrict__ hb,
                                              const int* __restrict__ batch,
                                              float* __restrict__ pp,   // [PB][NG][DD]
                                              int* __restrict__ pc) {   // [PB][NG]
    __shared__ float sacc[NG][DD];
    __shared__ int scnt[NG];
    const int tid = threadIdx.x;
    const int rs = tid >> 4;
    const int co = tid & 15;
#pragma unroll
    for (int j = 0; j < 4; ++j) sacc[(tid * 4 + j) >> 7][(tid * 4 + j) & 127] = 0.f;
    if (tid < NG) scnt[tid] = 0;
    __syncthreads();
    const int chunk = (NN + PB - 1) / PB;
    int lo = blockIdx.x * chunk;
    int hi = lo + chunk; if (hi > NN) hi = NN;
    const uint4* hp = (const uint4*)hb;
    float a[8] = {};
    int cur = -1, cnt = 0;
    for (int n = lo + rs; n < hi; n += 16) {
        int g = batch[n];
        if (g != cur) {
            if (cur >= 0) {
#pragma unroll
                for (int j = 0; j < 8; ++j) atomicAdd(&sacc[cur][co * 8 + j], a[j]);
                if (co == 0) atomicAdd(&scnt[cur], cnt);
#pragma unroll
                for (int j = 0; j < 8; ++j) a[j] = 0.f;
                cnt = 0;
            }
            cur = g;
        }
        uint4 v = hp[(size_t)n * 16 + co];
        a[0] += bflo(v.x); a[1] += bfhi(v.x);
        a[2] += bflo(v.y); a[3] += bfhi(v.y);
        a[4] += bflo(v.z); a[5] += bfhi(v.z);
        a[6] += bflo(v.w); a[7] += bfhi(v.w);
        cnt++;
    }
    if (cur >= 0) {
#pragma unroll
        for (int j = 0; j < 8; ++j) atomicAdd(&sacc[cur][co * 8 + j], a[j]);
        if (co == 0) atomicAdd(&scnt[cur], cnt);
    }
    __syncthreads();
    float* ppb = pp + (size_t)blockIdx.x * NG * DD;
#pragma unroll
    for (int j = 0; j < 4; ++j) {
        int idx = tid * 4 + j;
        ppb[idx] = sacc[idx >> 7][idx & 127];
    }
    if (tid < NG) pc[blockIdx.x * NG + tid] = scnt[tid];
}

// ---------------- head: reduce partials + final BN + dense + mu ----------------

__global__ __launch_bounds__(1024) void k_head(const float* __restrict__ pp,
                                               const int* __restrict__ pc,
                                               const float* __restrict__ statsP,
                                               const float* __restrict__ gammaP,
                                               const float* __restrict__ betaP,
                                               const float* __restrict__ dw,
                                               const float* __restrict__ db,
                                               const float* __restrict__ muw,
                                               const float* __restrict__ mub,
                                               float* __restrict__ out) {
    __shared__ float pm[NG][DD];
    __shared__ float zs[NG][DD];
    int t = threadIdx.x;
    int g = t >> 7, c = t & 127;
    float sum = 0.f;
    for (int b = 0; b < PB; ++b)
        sum += pp[(size_t)b * NG * DD + g * DD + c];
    int cnti = 0;
    for (int b = 0; b < PB; ++b)
        cnti += pc[b * NG + g];
    float cntg = (float)cnti;
    float sm = 0.f, qm = 0.f;
#pragma unroll
    for (int rr = 0; rr < SREP; ++rr) {
        sm += statsP[rr * 256 + c];
        qm += statsP[rr * 256 + DD + c];
    }
    float m = sm * (1.0f / NN);
    float var = qm * (1.0f / NN) - m * m;
    float s = gammaP[c] * rsqrtf(var + BN_EPS);
    float tv = betaP[c] - m * s;
    pm[g][c] = fmaf(s, sum, tv * cntg) / fmaxf(cntg, 1.0f);
    __syncthreads();
    float acc = 0.f;
    for (int k = 0; k < DD; ++k)
        acc = fmaf(pm[g][k], dw[k * DD + c], acc);
    float z = fmaxf(acc + db[c], 0.f);
    zs[g][c] = z * muw[c];
    __syncthreads();
    if (c == 0) {
        float s2 = 0.f;
        for (int k = 0; k < DD; ++k) s2 += zs[g][k];
        out[g] = s2 + mub[0];
    }
}

// ---------------- host ----------------

extern "C" void kernel_launch(void* const* d_in, const int* in_sizes, int n_in,
                              void* d_out, int out_size, void* d_ws, size_t ws_size,
                              hipStream_t stream) {
    const float* x      = (const float*)d_in[0];
    const int*   ei     = (const int*)d_in[1];
    const int*   batch  = (const int*)d_in[2];
    const float* W_rel  = (const float*)d_in[3];
    const float* b_rel  = (const float*)d_in[4];
    const float* W_root = (const float*)d_in[5];
    const float* gamma  = (const float*)d_in[6];
    const float* beta   = (const float*)d_in[7];
    const float* dw     = (const float*)d_in[8];
    const float* db     = (const float*)d_in[9];
    const float* muw    = (const float*)d_in[10];
    const float* mub    = (const float*)d_in[11];
    float* out = (float*)d_out;

    char* w = (char*)d_ws;
    auto alloc = [&](size_t bytes) {
        char* p = w;
        w += (bytes + 255) & ~(size_t)255;
        return p;
    };
    int*    off      = (int*)alloc((size_t)(NN + 1) * 4);
    int*    csr      = (int*)alloc((size_t)NE * 4);
    char*   bigbuf   = (char*)alloc((size_t)NN * DD * 4);   // CSR partition scratch
    unsigned short* hbA = (unsigned short*)alloc((size_t)NN * DD * 2);
    unsigned short* hbB = (unsigned short*)alloc((size_t)NN * DD * 2);
    float*  degf     = (float*)alloc((size_t)NN * 4);
    float*  statsBuf = (float*)alloc((size_t)NLAYERS * SREP * 2 * DD * 4);
    float*  biast    = (float*)alloc(2 * DD * 4);
    float*  pp       = (float*)alloc((size_t)PB * NG * DD * 4);
    int*    pc       = (int*)alloc((size_t)PB * NG * 4);
    int*    bincur   = (int*)alloc(256 * 4);
    int*    binbase  = (int*)alloc(256 * 4);
    __bf16* wfrag    = (__bf16*)alloc((size_t)65536 * 2);   // 128 KB, rewritten per layer

    const int* src = ei;
    const int* dst = ei + NE;
    unsigned* scratch = (unsigned*)bigbuf;  // 8.03 MB packed (CSR build only)

    hipMemsetAsync(bincur, 0, 256 * 4, stream);
    hipMemsetAsync(statsBuf, 0, (size_t)NLAYERS * SREP * 2 * DD * 4, stream);
    k_part<<<(NE + EPB - 1) / EPB, 1024, 0, stream>>>(src, dst, bincur, scratch);
    k_binscan<<<1, 256, 0, stream>>>(bincur, binbase, off);
    k_csr<<<NBIN, 1024, 0, stream>>>(bincur, binbase, scratch, off, csr, degf);
    k_xtobf<<<(NN * DD / 8 + 255) / 256, 256, 0, stream>>>(x, hbA);

    const unsigned short* hcur = hbA;
    unsigned short* bufs[2] = {hbB, hbA};
    for (int i = 0; i < NLAYERS; ++i) {
        unsigned short* hnext = bufs[i & 1];
        k_prep<<<17, 256, 0, stream>>>(W_rel + (size_t)i * DD * DD,
                                       W_root + (size_t)i * DD * DD,
                                       b_rel + (size_t)i * DD,
                                       gamma + (size_t)(i - 1) * DD,
                                       beta + (size_t)(i - 1) * DD,
                                       statsBuf + (size_t)(i - 1) * SREP * 2 * DD,
                                       i == 0 ? 1 : 0, wfrag, biast);
        k_layer<<<NN / 16, 256, 0, stream>>>(hcur, off, csr, wfrag, biast, degf,
                                             hnext, statsBuf + (size_t)i * SREP * 2 * DD);
        hcur = hnext;
    }
    k_pool<<<PB, 256, 0, stream>>>(hcur, batch, pp, pc);
    k_head<<<1, 1024, 0, stream>>>(pp, pc,
                                   statsBuf + (size_t)(NLAYERS - 1) * SREP * 2 * DD,
                                   gamma + (size_t)(NLAYERS - 1) * DD,
                                   beta + (size_t)(NLAYERS - 1) * DD,
                                   dw, db, muw, mub, out);
}

// Round 17
// 513.441 us; speedup vs baseline: 1.3391x; 1.0007x over previous
//
#include <hip/hip_runtime.h>

#define NN 50000
#define NE 1600000
#define DD 128
#define NLAYERS 6
#define NG 8
#define BN_EPS 1e-5f

#define NBIN 196       // bins of 256 dst nodes
#define BINCAP 10240   // avg 8163/bin, sigma~90 -> +22 sigma headroom
#define EPB 8192       // edges per k_part block
#define PB 128         // pool partial blocks
#define SREP 8         // stats replicas (atomic contention / 8)

typedef __bf16 bf16x8 __attribute__((ext_vector_type(8)));
typedef float f32x4 __attribute__((ext_vector_type(4)));

static __device__ __forceinline__ float bflo(unsigned u) {
    return __uint_as_float(u << 16);
}
static __device__ __forceinline__ float bfhi(unsigned u) {
    return __uint_as_float(u & 0xffff0000u);
}
static __device__ __forceinline__ unsigned pkbf(float a, float b) {
    __bf16 x = (__bf16)a, y = (__bf16)b;
    return (unsigned)*(unsigned short*)&x | ((unsigned)*(unsigned short*)&y << 16);
}

// ---------------- CSR build: 2-pass bin partition, packed 4B scratch ----------
// scratch entry = (src << 8) | (dst & 255)   [src < 65536, bin-local dst]

__global__ __launch_bounds__(1024) void k_part(const int* __restrict__ src,
                                               const int* __restrict__ dst,
                                               int* __restrict__ bincur,
                                               unsigned* __restrict__ scratch) {
    __shared__ int lh[NBIN], lbase[NBIN];
    const int t = threadIdx.x;
    const int e0 = blockIdx.x * EPB;
    int s8[8], d8[8];
#pragma unroll
    for (int j = 0; j < 8; ++j) {
        int e = e0 + j * 1024 + t;
        if (e < NE) { s8[j] = src[e]; d8[j] = dst[e]; }
        else d8[j] = -1;
    }
    if (t < NBIN) lh[t] = 0;
    __syncthreads();
#pragma unroll
    for (int j = 0; j < 8; ++j)
        if (d8[j] >= 0) atomicAdd(&lh[d8[j] >> 8], 1);
    __syncthreads();
    if (t < NBIN) {
        int c = lh[t];
        lbase[t] = c ? atomicAdd(&bincur[t], c) : 0;
        lh[t] = 0;
    }
    __syncthreads();
#pragma unroll
    for (int j = 0; j < 8; ++j)
        if (d8[j] >= 0) {
            int b = d8[j] >> 8;
            int p = lbase[b] + atomicAdd(&lh[b], 1);
            if (p < BINCAP)
                scratch[(size_t)b * BINCAP + p] = ((unsigned)s8[j] << 8) | (unsigned)(d8[j] & 255);
        }
}

__global__ __launch_bounds__(256) void k_binscan(const int* __restrict__ bincur,
                                                 int* __restrict__ binbase,
                                                 int* __restrict__ off) {
    __shared__ int sc[256];
    int t = threadIdx.x;
    sc[t] = (t < NBIN) ? bincur[t] : 0;
    __syncthreads();
    for (int d = 1; d < 256; d <<= 1) {
        int v = (t >= d) ? sc[t - d] : 0;
        __syncthreads();
        sc[t] += v;
        __syncthreads();
    }
    binbase[t] = (t == 0) ? 0 : sc[t - 1];
    if (t == 0) off[NN] = NE;
}

__global__ __launch_bounds__(1024) void k_csr(const int* __restrict__ bincur,
                                              const int* __restrict__ binbase,
                                              const unsigned* __restrict__ scratch,
                                              int* __restrict__ off,
                                              int* __restrict__ csr,
                                              float* __restrict__ degf) {
    __shared__ int nh[256], no[256], ncur[256];
    const int t = threadIdx.x;
    const int b = blockIdx.x;
    int cnt = bincur[b]; if (cnt > BINCAP) cnt = BINCAP;
    const int base = binbase[b];
    if (t < 256) nh[t] = 0;
    __syncthreads();
    for (int i = t; i < cnt; i += 1024) {
        unsigned p = scratch[(size_t)b * BINCAP + i];
        atomicAdd(&nh[p & 255], 1);
    }
    __syncthreads();
    if (t < 256) no[t] = nh[t];
    __syncthreads();
    for (int d = 1; d < 256; d <<= 1) {
        int v = 0;
        if (t < 256 && t >= d) v = no[t - d];
        __syncthreads();
        if (t < 256) no[t] += v;
        __syncthreads();
    }
    if (t < 256) {
        int excl = (t == 0) ? 0 : no[t - 1];
        ncur[t] = excl;
        int n = b * 256 + t;
        if (n < NN) {
            off[n] = base + excl;
            degf[n] = (float)nh[t];
        }
    }
    __syncthreads();
    for (int i = t; i < cnt; i += 1024) {
        unsigned p = scratch[(size_t)b * BINCAP + i];
        int pos = atomicAdd(&ncur[p & 255], 1);
        csr[base + pos] = (int)(p >> 8);
    }
}

// ---------------- x -> bf16 copy ----------------

__global__ __launch_bounds__(256) void k_xtobf(const float* __restrict__ x,
                                               unsigned short* __restrict__ xb) {
    size_t i = (size_t)(blockIdx.x * 256 + threadIdx.x) * 8;
    float4 a = *(const float4*)(x + i);
    float4 b = *(const float4*)(x + i + 4);
    uint4 o;
    o.x = pkbf(a.x, a.y); o.y = pkbf(a.z, a.w);
    o.z = pkbf(b.x, b.y); o.w = pkbf(b.z, b.w);
    *(uint4*)(xb + i) = o;
}

// ---------------- per-layer weight prep (BN fold; LDS-cached s/tv) ------------

__global__ __launch_bounds__(256) void k_prep(const float* __restrict__ Wrel,
                                              const float* __restrict__ Wroot,
                                              const float* __restrict__ brel,
                                              const float* __restrict__ gammaP,
                                              const float* __restrict__ betaP,
                                              const float* __restrict__ statsP,
                                              int first,
                                              __bf16* __restrict__ wfrag,
                                              float* __restrict__ biast) {
    __shared__ float ls[DD], lt[DD];
    int t0 = threadIdx.x;
    if (t0 < DD) {
        float s = 1.f, tv = 0.f;
        if (!first) {
            float sm = 0.f, qm = 0.f;
#pragma unroll
            for (int rr = 0; rr < SREP; ++rr) {
                sm += statsP[rr * 256 + t0];
                qm += statsP[rr * 256 + DD + t0];
            }
            float m = sm * (1.0f / NN);
            float var = qm * (1.0f / NN) - m * m;
            s = gammaP[t0] * rsqrtf(var + BN_EPS);
            tv = betaP[t0] - m * s;
        }
        ls[t0] = s;
        lt[t0] = tv;
    }
    __syncthreads();
    int b = blockIdx.x;
    if (b < 16) {
        int gid = b * 256 + threadIdx.x;       // 4096 tasks
        int pass = gid >> 11;
        int r = gid & 2047;
        int ks = r >> 9;
        int r2 = r & 511;
        int ct = r2 >> 6;
        int lane = r2 & 63;
        int col = ct * 16 + (lane & 15);
        int kb = ks * 32 + (lane >> 4) * 8;
        const float* W = pass ? Wroot : Wrel;
        bf16x8 vh, vl;
#pragma unroll
        for (int j = 0; j < 8; ++j) {
            int k = kb + j;
            float v = ls[k] * W[(size_t)k * DD + col];
            __bf16 hb = (__bf16)v;
            vh[j] = hb;
            vl[j] = (__bf16)(v - (float)hb);
        }
        size_t oh = (((size_t)(pass * 2 + 0) * 4 + ks) * 8 + ct) * 512 + lane * 8;
        *(bf16x8*)(wfrag + oh) = vh;
        *(bf16x8*)(wfrag + oh + 16384) = vl;
    } else {
        int t = threadIdx.x;
        int col = t & 127;
        bool isT = t >= 128;
        const float* W = isT ? Wrel : Wroot;
        float acc = 0.f;
        if (!first) {
            for (int k = 0; k < DD; ++k)
                acc = fmaf(lt[k], W[(size_t)k * DD + col], acc);
        }
        if (isT) biast[128 + col] = acc;
        else biast[col] = brel[col] + acc;
    }
}

// ---------------- fused layer (R14 structure, 8 blocks/CU residency) ----------

#define ACC8(v) {                                              \
    a0 += bflo(v.x); a1 += bfhi(v.x);                          \
    a2 += bflo(v.y); a3 += bfhi(v.y);                          \
    a4 += bflo(v.z); a5 += bfhi(v.z);                          \
    a6 += bflo(v.w); a7 += bfhi(v.w); }

__global__ __launch_bounds__(256, 8) void k_layer(const unsigned short* __restrict__ hb_in,
                                                  const int* __restrict__ off,
                                                  const int* __restrict__ csr,
                                                  const __bf16* __restrict__ wfrag,
                                                  const float* __restrict__ biast,
                                                  const float* __restrict__ degf,
                                                  unsigned short* __restrict__ hb_out,
                                                  float* __restrict__ stats) {
    __shared__ __align__(16) __bf16 A_hi[16 * 128];
    __shared__ __align__(16) __bf16 A_lo[16 * 128];
    __shared__ float sb[4][32], qb[4][32];
    const int tid = threadIdx.x;
    const int w = tid >> 6, lane = tid & 63;
    const int r0 = blockIdx.x * 16;          // 3125 blocks cover NN exactly

    // ---- Phase G: wave w gathers rows w*4 .. w*4+3 ----
    {
        const int q = lane >> 4;
        const int colo = lane & 15;
        const uint4* hp = (const uint4*)hb_in;
#pragma unroll 1
        for (int rr = 0; rr < 4; ++rr) {
            int r = w * 4 + rr;
            int n = r0 + r;
            float a0 = 0.f, a1 = 0.f, a2 = 0.f, a3 = 0.f,
                  a4 = 0.f, a5 = 0.f, a6 = 0.f, a7 = 0.f;
            int lo = off[n], hi = off[n + 1];
            int e = lo;
            for (; e + 16 <= hi; e += 16) {
                int s0 = csr[e + q];
                int s1 = csr[e + 4 + q];
                int s2 = csr[e + 8 + q];
                int s3 = csr[e + 12 + q];
                uint4 v0 = hp[(size_t)s0 * 16 + colo];
                uint4 v1 = hp[(size_t)s1 * 16 + colo];
                uint4 v2 = hp[(size_t)s2 * 16 + colo];
                uint4 v3 = hp[(size_t)s3 * 16 + colo];
                ACC8(v0); ACC8(v1); ACC8(v2); ACC8(v3);
            }
            for (; e + 4 <= hi; e += 4) {
                int s = csr[e + q];
                uint4 v = hp[(size_t)s * 16 + colo];
                ACC8(v);
            }
            a0 += __shfl_xor(a0, 16); a1 += __shfl_xor(a1, 16);
            a2 += __shfl_xor(a2, 16); a3 += __shfl_xor(a3, 16);
            a4 += __shfl_xor(a4, 16); a5 += __shfl_xor(a5, 16);
            a6 += __shfl_xor(a6, 16); a7 += __shfl_xor(a7, 16);
            a0 += __shfl_xor(a0, 32); a1 += __shfl_xor(a1, 32);
            a2 += __shfl_xor(a2, 32); a3 += __shfl_xor(a3, 32);
            a4 += __shfl_xor(a4, 32); a5 += __shfl_xor(a5, 32);
            a6 += __shfl_xor(a6, 32); a7 += __shfl_xor(a7, 32);
            for (; e < hi; ++e) {  // tail: all lanes add identical values
                int s = csr[e];
                uint4 v = hp[(size_t)s * 16 + colo];
                ACC8(v);
            }
            if (lane < 16) {
                float av[8] = {a0, a1, a2, a3, a4, a5, a6, a7};
                bf16x8 vh, vl;
#pragma unroll
                for (int j = 0; j < 8; ++j) {
                    __bf16 hv = (__bf16)av[j];
                    vh[j] = hv;
                    vl[j] = (__bf16)(av[j] - (float)hv);
                }
                int eo = r * 128 + ((colo ^ (r & 7)) << 3);
                *(bf16x8*)(A_hi + eo) = vh;
                *(bf16x8*)(A_lo + eo) = vl;
            }
        }
    }
    __syncthreads();

    // ---- Phase M: 16x128 gemm; wave w = col-group (32 cols) ----
    const int cg = w;
    const int lrow = lane & 15, lk = lane >> 4;
    const int nA = r0 + lrow;                // < NN always

    f32x4 acc[2];
    acc[0] = (f32x4){0.f, 0.f, 0.f, 0.f};
    acc[1] = (f32x4){0.f, 0.f, 0.f, 0.f};

#pragma unroll
    for (int pass = 0; pass < 2; ++pass) {
#pragma unroll
        for (int ks = 0; ks < 4; ++ks) {
            bf16x8 ah, al;
            if (pass == 0) {
                int chA = ks * 4 + lk;
                int eoA = lrow * 128 + ((chA ^ (lrow & 7)) << 3);
                ah = *(const bf16x8*)(A_hi + eoA);
                al = *(const bf16x8*)(A_lo + eoA);
            } else {
                ah = *(const bf16x8*)(hb_in + (size_t)nA * DD + ks * 32 + lk * 8);
            }
            const __bf16* bh_base = wfrag + ((size_t)(pass * 2 + 0) * 4 + ks) * 4096
                                    + (cg * 2) * 512 + lane * 8;
            const __bf16* bl_base = wfrag + ((size_t)(pass * 2 + 1) * 4 + ks) * 4096
                                    + (cg * 2) * 512 + lane * 8;
#pragma unroll
            for (int ctl = 0; ctl < 2; ++ctl) {
                bf16x8 bh = *(const bf16x8*)(bh_base + ctl * 512);
                bf16x8 bl = *(const bf16x8*)(bl_base + ctl * 512);
                acc[ctl] = __builtin_amdgcn_mfma_f32_16x16x32_bf16(ah, bh, acc[ctl], 0, 0, 0);
                if (pass == 0)
                    acc[ctl] = __builtin_amdgcn_mfma_f32_16x16x32_bf16(al, bh, acc[ctl], 0, 0, 0);
                acc[ctl] = __builtin_amdgcn_mfma_f32_16x16x32_bf16(ah, bl, acc[ctl], 0, 0, 0);
            }
        }
    }

    // ---- epilogue: bias + relu + store + column stats (SREP-replicated) ----
    float cs[2], cq[2];
    cs[0] = cs[1] = cq[0] = cq[1] = 0.f;
#pragma unroll
    for (int ctl = 0; ctl < 2; ++ctl) {
        int col = (cg * 2 + ctl) * 16 + lrow;
        float bt = biast[col];
        float tr = biast[128 + col];
#pragma unroll
        for (int q2 = 0; q2 < 4; ++q2) {
            int n = r0 + lk * 4 + q2;
            float o = fmaxf(acc[ctl][q2] + bt + degf[n] * tr, 0.f);
            __bf16 ob = (__bf16)o;
            hb_out[(size_t)n * DD + col] = *(unsigned short*)&ob;
            cs[ctl] += o;
            cq[ctl] += o * o;
        }
    }
#pragma unroll
    for (int ctl = 0; ctl < 2; ++ctl) {
        cs[ctl] += __shfl_xor(cs[ctl], 16);
        cs[ctl] += __shfl_xor(cs[ctl], 32);
        cq[ctl] += __shfl_xor(cq[ctl], 16);
        cq[ctl] += __shfl_xor(cq[ctl], 32);
    }
    if (lane < 16) {
#pragma unroll
        for (int ctl = 0; ctl < 2; ++ctl) {
            sb[cg][ctl * 16 + lrow] = cs[ctl];
            qb[cg][ctl * 16 + lrow] = cq[ctl];
        }
    }
    __syncthreads();
    float* srep = stats + (size_t)(blockIdx.x & (SREP - 1)) * 256;
    if (tid < 128) {
        atomicAdd(&srep[tid], sb[tid >> 5][tid & 31]);
    } else if (tid < 256) {
        int c2 = tid - 128;
        atomicAdd(&srep[DD + c2], qb[c2 >> 5][c2 & 31]);
    }
}

// ---------------- pooling stage 1: per-block partials, no global atomics --------

__global__ __launch_bounds__(256) void k_pool(const unsigned short* __restrict__ hb,
                                              const int* __restrict__ batch,
                                              float* __restrict__ pp,   // [PB][NG][DD]
                                              int* __restrict__ pc) {   // [PB][NG]
    __shared__ float sacc[NG][DD];
    __shared__ int scnt[NG];
    const int tid = threadIdx.x;
    const int rs = tid >> 4;
    const int co = tid & 15;
#pragma unroll
    for (int j = 0; j < 4; ++j) sacc[(tid * 4 + j) >> 7][(tid * 4 + j) & 127] = 0.f;
    if (tid < NG) scnt[tid] = 0;
    __syncthreads();
    const int chunk = (NN + PB - 1) / PB;
    int lo = blockIdx.x * chunk;
    int hi = lo + chunk; if (hi > NN) hi = NN;
    const uint4* hp = (const uint4*)hb;
    float a[8] = {};
    int cur = -1, cnt = 0;
    for (int n = lo + rs; n < hi; n += 16) {
        int g = batch[n];
        if (g != cur) {
            if (cur >= 0) {
#pragma unroll
                for (int j = 0; j < 8; ++j) atomicAdd(&sacc[cur][co * 8 + j], a[j]);
                if (co == 0) atomicAdd(&scnt[cur], cnt);
#pragma unroll
                for (int j = 0; j < 8; ++j) a[j] = 0.f;
                cnt = 0;
            }
            cur = g;
        }
        uint4 v = hp[(size_t)n * 16 + co];
        a[0] += bflo(v.x); a[1] += bfhi(v.x);
        a[2] += bflo(v.y); a[3] += bfhi(v.y);
        a[4] += bflo(v.z); a[5] += bfhi(v.z);
        a[6] += bflo(v.w); a[7] += bfhi(v.w);
        cnt++;
    }
    if (cur >= 0) {
#pragma unroll
        for (int j = 0; j < 8; ++j) atomicAdd(&sacc[cur][co * 8 + j], a[j]);
        if (co == 0) atomicAdd(&scnt[cur], cnt);
    }
    __syncthreads();
    float* ppb = pp + (size_t)blockIdx.x * NG * DD;
#pragma unroll
    for (int j = 0; j < 4; ++j) {
        int idx = tid * 4 + j;
        ppb[idx] = sacc[idx >> 7][idx & 127];
    }
    if (tid < NG) pc[blockIdx.x * NG + tid] = scnt[tid];
}

// ---------------- head: reduce partials + final BN + dense + mu ----------------

__global__ __launch_bounds__(1024) void k_head(const float* __restrict__ pp,
                                               const int* __restrict__ pc,
                                               const float* __restrict__ statsP,
                                               const float* __restrict__ gammaP,
                                               const float* __restrict__ betaP,
                                               const float* __restrict__ dw,
                                               const float* __restrict__ db,
                                               const float* __restrict__ muw,
                                               const float* __restrict__ mub,
                                               float* __restrict__ out) {
    __shared__ float pm[NG][DD];
    __shared__ float zs[NG][DD];
    int t = threadIdx.x;
    int g = t >> 7, c = t & 127;
    float sum = 0.f;
    for (int b = 0; b < PB; ++b)
        sum += pp[(size_t)b * NG * DD + g * DD + c];
    int cnti = 0;
    for (int b = 0; b < PB; ++b)
        cnti += pc[b * NG + g];
    float cntg = (float)cnti;
    float sm = 0.f, qm = 0.f;
#pragma unroll
    for (int rr = 0; rr < SREP; ++rr) {
        sm += statsP[rr * 256 + c];
        qm += statsP[rr * 256 + DD + c];
    }
    float m = sm * (1.0f / NN);
    float var = qm * (1.0f / NN) - m * m;
    float s = gammaP[c] * rsqrtf(var + BN_EPS);
    float tv = betaP[c] - m * s;
    pm[g][c] = fmaf(s, sum, tv * cntg) / fmaxf(cntg, 1.0f);
    __syncthreads();
    float acc = 0.f;
    for (int k = 0; k < DD; ++k)
        acc = fmaf(pm[g][k], dw[k * DD + c], acc);
    float z = fmaxf(acc + db[c], 0.f);
    zs[g][c] = z * muw[c];
    __syncthreads();
    if (c == 0) {
        float s2 = 0.f;
        for (int k = 0; k < DD; ++k) s2 += zs[g][k];
        out[g] = s2 + mub[0];
    }
}

// ---------------- host ----------------

extern "C" void kernel_launch(void* const* d_in, const int* in_sizes, int n_in,
                              void* d_out, int out_size, void* d_ws, size_t ws_size,
                              hipStream_t stream) {
    const float* x      = (const float*)d_in[0];
    const int*   ei     = (const int*)d_in[1];
    const int*   batch  = (const int*)d_in[2];
    const float* W_rel  = (const float*)d_in[3];
    const float* b_rel  = (const float*)d_in[4];
    const float* W_root = (const float*)d_in[5];
    const float* gamma  = (const float*)d_in[6];
    const float* beta   = (const float*)d_in[7];
    const float* dw     = (const float*)d_in[8];
    const float* db     = (const float*)d_in[9];
    const float* muw    = (const float*)d_in[10];
    const float* mub    = (const float*)d_in[11];
    float* out = (float*)d_out;

    char* w = (char*)d_ws;
    auto alloc = [&](size_t bytes) {
        char* p = w;
        w += (bytes + 255) & ~(size_t)255;
        return p;
    };
    int*    off      = (int*)alloc((size_t)(NN + 1) * 4);
    int*    csr      = (int*)alloc((size_t)NE * 4);
    char*   bigbuf   = (char*)alloc((size_t)NN * DD * 4);   // CSR partition scratch
    unsigned short* hbA = (unsigned short*)alloc((size_t)NN * DD * 2);
    unsigned short* hbB = (unsigned short*)alloc((size_t)NN * DD * 2);
    float*  degf     = (float*)alloc((size_t)NN * 4);
    float*  statsBuf = (float*)alloc((size_t)NLAYERS * SREP * 2 * DD * 4);
    float*  biast    = (float*)alloc(2 * DD * 4);
    float*  pp       = (float*)alloc((size_t)PB * NG * DD * 4);
    int*    pc       = (int*)alloc((size_t)PB * NG * 4);
    int*    bincur   = (int*)alloc(256 * 4);
    int*    binbase  = (int*)alloc(256 * 4);
    __bf16* wfrag    = (__bf16*)alloc((size_t)65536 * 2);   // 128 KB, rewritten per layer

    const int* src = ei;
    const int* dst = ei + NE;
    unsigned* scratch = (unsigned*)bigbuf;  // 8.03 MB packed (CSR build only)

    hipMemsetAsync(bincur, 0, 256 * 4, stream);
    hipMemsetAsync(statsBuf, 0, (size_t)NLAYERS * SREP * 2 * DD * 4, stream);
    k_part<<<(NE + EPB - 1) / EPB, 1024, 0, stream>>>(src, dst, bincur, scratch);
    k_binscan<<<1, 256, 0, stream>>>(bincur, binbase, off);
    k_csr<<<NBIN, 1024, 0, stream>>>(bincur, binbase, scratch, off, csr, degf);
    k_xtobf<<<(NN * DD / 8 + 255) / 256, 256, 0, stream>>>(x, hbA);

    const unsigned short* hcur = hbA;
    unsigned short* bufs[2] = {hbB, hbA};
    for (int i = 0; i < NLAYERS; ++i) {
        unsigned short* hnext = bufs[i & 1];
        k_prep<<<17, 256, 0, stream>>>(W_rel + (size_t)i * DD * DD,
                                       W_root + (size_t)i * DD * DD,
                                       b_rel + (size_t)i * DD,
                                       gamma + (size_t)(i - 1) * DD,
                                       beta + (size_t)(i - 1) * DD,
                                       statsBuf + (size_t)(i - 1) * SREP * 2 * DD,
                                       i == 0 ? 1 : 0, wfrag, biast);
        k_layer<<<NN / 16, 256, 0, stream>>>(hcur, off, csr, wfrag, biast, degf,
                                             hnext, statsBuf + (size_t)i * SREP * 2 * DD);
        hcur = hnext;
    }
    k_pool<<<PB, 256, 0, stream>>>(hcur, batch, pp, pc);
    k_head<<<1, 1024, 0, stream>>>(pp, pc,
                                   statsBuf + (size_t)(NLAYERS - 1) * SREP * 2 * DD,
                                   gamma + (size_t)(NLAYERS - 1) * DD,
                                   beta + (size_t)(NLAYERS - 1) * DD,
                                   dw, db, muw, mub, out);
}